// Round 13
// baseline (980.046 us; speedup 1.0000x reference)
//
#include <hip/hip_runtime.h>
#include <stdint.h>

// ---------------- problem constants ----------------
constexpr int N_   = 20000;
constexpr int E_   = 160000;
constexpr int C_   = 64;
constexpr int K_   = 2000;
constexpr int EV_  = 32000;
constexpr int EALL_ = E_ + EV_;          // 192000
constexpr int CSH_ = 576;                // C*SH
constexpr int TB_  = 64;                 // edges per block in batched conv
constexpr int NFLAT_ = K_ * K_;          // 4,000,000

// ---------------- workspace layout (bytes) ----------------
constexpr size_t OFF_AGG    = 0;                  // N*C f32
constexpr size_t OFF_DEG    = 5120000;            // N f32
constexpr size_t OFF_AGGM   = 5200000;            // K*C f32
constexpr size_t OFF_DEGM   = 5712000;            // K f32
constexpr size_t OFF_RANK   = 5720000;            // N i32
constexpr size_t OFF_MASKA  = 5800000;            // EALL f32
constexpr size_t OFF_EXIST  = 6568000;            // K*K u8
constexpr size_t OFF_HIST   = 10568000;           // 1024 u32
constexpr size_t OFF_STATE  = 10572096;           // RState + counters 256  (zeroed by k_init)
// [ non-zero region ]
constexpr size_t OFF_HLOCAL = 10572352;           // N*C f32
constexpr size_t OFF_KEY    = 15692352;           // N u64
constexpr size_t OFF_SCORE  = 15852352;           // N f32
constexpr size_t OFF_N2M    = 15932352;           // N i32
constexpr size_t OFF_MIDX   = 16012352;           // K i32
constexpr size_t OFF_HM     = 16020352;           // K*C f32
constexpr size_t OFF_POSM   = 16532352;           // K*3 f32
constexpr size_t OFF_Q      = 16556352;           // K*16 f32
constexpr size_t OFF_KBUF   = 16684352;           // K*16 f32
constexpr size_t OFF_SRCA   = 16812352;           // EALL i32
constexpr size_t OFF_DSTA   = 17580352;           // EALL i32
constexpr size_t OFF_WMAX   = 18348352;           // 62500 f32 per-wave attn max
constexpr size_t OFF_CAND   = 18598400;           // cand keys / edata overlay
// total used ~38.7 MB

struct RState {
    unsigned long long prefix;
    int R;
    unsigned int cand_count;
    unsigned int sel_count;
    int bin_thresh;
    unsigned int total;
    unsigned int pad;
};
// state area: RState +0, cnt0 +64, cnt1 +68, w0nz +72, done_a1 +76, done_rk +80, done_a2 +84

// ---------------- k_init: zero workspace + (last block) state zero + w0nz ----------------
__global__ __launch_bounds__(256) void k_init(const float* __restrict__ fc_b1,
    const float* __restrict__ fc_w2, const float* __restrict__ fc_b2, char* __restrict__ ws)
{
    float4 zero4 = make_float4(0.f, 0.f, 0.f, 0.f);
    float4* z = (float4*)ws;
    int nz4 = (int)(OFF_STATE / 16);
    for (int i = blockIdx.x * 256 + threadIdx.x; i < nz4; i += gridDim.x * 256) z[i] = zero4;
    if (blockIdx.x == gridDim.x - 1) {
        __shared__ float hid0[64];
        __shared__ int nz;
        int t = threadIdx.x;
        float4* zs = (float4*)(ws + OFF_STATE);
        if (t < 16) zs[t] = zero4;
        if (t == 0) nz = 0;
        if (t < 64) hid0[t] = fmaxf(fc_b1[t], 0.0f);
        __syncthreads();
        for (int j = t; j < CSH_; j += 256) {
            float acc = fc_b2[j];
            for (int k = 0; k < 64; k++) acc += hid0[k] * fc_w2[k * CSH_ + j];
            if (acc != 0.0f) atomicOr(&nz, 1);
        }
        __syncthreads();
        if (t == 0) *(int*)(ws + OFF_STATE + 72) = nz;
    }
}

// ---------------- edge prep ----------------
__global__ __launch_bounds__(256) void k_prep(
    int n_edges, const int* __restrict__ src, const int* __restrict__ dst,
    const float* __restrict__ mask, const float* __restrict__ posn,
    const int* __restrict__ w0nz, float* __restrict__ deg,
    float* __restrict__ edata, unsigned int* __restrict__ cnt)
{
    int e = blockIdx.x * 256 + threadIdx.x;
    bool valid = e < n_edges;
    int s_i = 0, d_i = 0; float msk = 0.0f;
    if (valid) {
        msk = mask ? mask[e] : 1.0f;
        if (msk != 0.0f) { s_i = src[e]; d_i = dst[e]; }
    }
    bool active = valid && (msk != 0.0f);

    float vx = 0.f, vy = 0.f, vz = 0.f;
    if (active) {
        vx = posn[s_i*3+0] - posn[d_i*3+0];
        vy = posn[s_i*3+1] - posn[d_i*3+1];
        vz = posn[s_i*3+2] - posn[d_i*3+2];
    }
    float r = sqrtf(vx*vx + vy*vy + vz*vz + 1e-12f);
    float invr = 1.0f / r;
    float x = vx*invr, y = vy*invr, z = vz*invr;
    const float s3 = 1.7320508075688772f, s15 = 3.872983346207417f, s5 = 2.23606797749979f;
    float sh[9];
    sh[0] = 1.0f; sh[1] = s3*x; sh[2] = s3*y; sh[3] = s3*z;
    sh[4] = s15*x*y; sh[5] = s15*y*z; sh[6] = 0.5f*s5*(3.0f*z*z - 1.0f);
    sh[7] = s15*x*z; sh[8] = 0.5f*s15*(x*x - y*y);

    float u = r * 0.2f; u = u > 1.0f ? 1.0f : u;
    float u2 = u*u, u6 = u2*u2*u2, u7 = u6*u, u8 = u7*u;
    float env = 1.0f - 28.0f*u6 + 48.0f*u7 - 21.0f*u8;
    float rc = r > 1e-9f ? r : 1e-9f;
    const float bpref = 0.6324555320336759f;      // sqrt(2/5)
    const float PIov5 = 0.6283185307179586f;
    float ef[8];
    #pragma unroll
    for (int n = 0; n < 8; n++)
        ef[n] = bpref * sinf(PIov5 * r * (float)(n + 1)) / rc * env;

    if (active) atomicAdd(&deg[s_i], msk);

    bool contrib = active && !((env == 0.0f) && (*w0nz == 0));
    int lane = threadIdx.x & 63;
    unsigned long long b = __ballot(contrib);
    int wc = __popcll(b);
    int base = 0;
    if (lane == 0 && wc) base = (int)atomicAdd(cnt, (unsigned)wc);
    base = __shfl(base, 0);
    if (contrib) {
        int slot = base + __popcll(b & ((1ull << lane) - 1ull));
        float* p = edata + (size_t)slot * 20;
        #pragma unroll
        for (int n = 0; n < 8; n++) p[n] = ef[n];
        #pragma unroll
        for (int t = 0; t < 9; t++) p[8+t] = sh[t];
        p[17] = __int_as_float(s_i);
        p[18] = __int_as_float(d_i);
        p[19] = msk;
    }
}

// ---------------- batched conv GEMM (R12-proven) ----------------
__global__ __launch_bounds__(256, 3) void k_convg(
    const unsigned int* __restrict__ cnt, const float* __restrict__ edata,
    const float* __restrict__ hn,
    const float* __restrict__ fc_w1, const float* __restrict__ fc_b1,
    const float* __restrict__ fc_w2, const float* __restrict__ fc_b2,
    const float* __restrict__ lin_w, float* __restrict__ agg)
{
    __shared__ float s_misc[TB_ * 12];
    __shared__ __align__(16) float s_hid[64 * 64];     // [k][e]
    __shared__ __align__(16) float s_tp[64 * 68];      // [j_local][e], stride 68
    __shared__ __align__(16) float s_w[4096];

    const int tid = threadIdx.x;
    const int oq = (tid & 15) * 4;
    const int e0 = (tid >> 4) * 4;

    const int nheavy = (int)*cnt;
    const int nblk = (nheavy + TB_ - 1) / TB_;

    for (int blk = blockIdx.x; blk < nblk; blk += gridDim.x) {
        const int ebase = blk * TB_;
        int nE = nheavy - ebase; if (nE > TB_) nE = TB_;

        __syncthreads();
        for (int idx = tid; idx < TB_ * 12; idx += 256) {
            int e = idx / 12, f = idx - 12 * e;
            float v = 0.0f;
            if (e < nE) {
                const float* p = edata + (size_t)(ebase + e) * 20;
                v = (f < 9) ? p[8 + f] : (f == 9) ? p[17] : (f == 10) ? p[19] : p[18];
            }
            s_misc[idx] = v;
        }
        for (int idx = tid; idx < TB_ * 64; idx += 256) {
            int k = idx >> 6, e = idx & 63;
            float hv = 0.0f;
            if (e < nE) {
                const float* p = edata + (size_t)(ebase + e) * 20;
                float acc = fc_b1[k];
                #pragma unroll
                for (int n = 0; n < 8; n++) acc += p[n] * fc_w1[n * 64 + k];
                hv = fmaxf(acc, 0.0f);
            }
            s_hid[k * 64 + e] = hv;
        }
        float acc[4][4] = {{0,0,0,0},{0,0,0,0},{0,0,0,0},{0,0,0,0}};
        __syncthreads();

        const int d0 = __float_as_int(s_misc[(e0+0) * 12 + 11]);
        const int d1 = __float_as_int(s_misc[(e0+1) * 12 + 11]);
        const int d2 = __float_as_int(s_misc[(e0+2) * 12 + 11]);
        const int d3 = __float_as_int(s_misc[(e0+3) * 12 + 11]);

        for (int cj = 0; cj < 9; cj++) {
            const int j0 = cj * 64;
            if (cj) __syncthreads();
            for (int i4 = tid; i4 < 1024; i4 += 256) {
                int k = i4 >> 4, q4 = (i4 & 15) * 4;
                *reinterpret_cast<float4*>(&s_w[k * 64 + q4]) =
                    *reinterpret_cast<const float4*>(&fc_w2[k * CSH_ + j0 + q4]);
            }
            __syncthreads();

            const int jb = j0 + oq;
            const int c0 = jb / 9, c1 = (jb + 3) / 9;
            float hA0 = hn[d0 * 64 + c0], hB0 = hn[d0 * 64 + c1];
            float hA1 = hn[d1 * 64 + c0], hB1 = hn[d1 * 64 + c1];
            float hA2 = hn[d2 * 64 + c0], hB2 = hn[d2 * 64 + c1];
            float hA3 = hn[d3 * 64 + c0], hB3 = hn[d3 * 64 + c1];

            float a[4][4];
            #pragma unroll
            for (int q = 0; q < 4; q++) {
                float b = fc_b2[jb + q];
                a[0][q]=b; a[1][q]=b; a[2][q]=b; a[3][q]=b;
            }
            #pragma unroll 4
            for (int k = 0; k < 64; k++) {
                float4 w4 = *reinterpret_cast<const float4*>(&s_w[k * 64 + oq]);
                float4 h4 = *reinterpret_cast<const float4*>(&s_hid[k * 64 + e0]);
                a[0][0]+=h4.x*w4.x; a[0][1]+=h4.x*w4.y; a[0][2]+=h4.x*w4.z; a[0][3]+=h4.x*w4.w;
                a[1][0]+=h4.y*w4.x; a[1][1]+=h4.y*w4.y; a[1][2]+=h4.y*w4.z; a[1][3]+=h4.y*w4.w;
                a[2][0]+=h4.z*w4.x; a[2][1]+=h4.z*w4.y; a[2][2]+=h4.z*w4.z; a[2][3]+=h4.z*w4.w;
                a[3][0]+=h4.w*w4.x; a[3][1]+=h4.w*w4.y; a[3][2]+=h4.w*w4.z; a[3][3]+=h4.w*w4.w;
            }
            #pragma unroll
            for (int q = 0; q < 4; q++) {
                int j = jb + q; int cc = j / 9; int si = j - 9 * cc;
                float4 tpv;
                tpv.x = (cc == c0 ? hA0 : hB0) * s_misc[(e0+0) * 12 + si] * a[0][q];
                tpv.y = (cc == c0 ? hA1 : hB1) * s_misc[(e0+1) * 12 + si] * a[1][q];
                tpv.z = (cc == c0 ? hA2 : hB2) * s_misc[(e0+2) * 12 + si] * a[2][q];
                tpv.w = (cc == c0 ? hA3 : hB3) * s_misc[(e0+3) * 12 + si] * a[3][q];
                *reinterpret_cast<float4*>(&s_tp[(oq + q) * 68 + e0]) = tpv;
            }
            __syncthreads();

            for (int i4 = tid; i4 < 1024; i4 += 256) {
                *reinterpret_cast<float4*>(&s_w[i4 * 4]) =
                    *reinterpret_cast<const float4*>(&lin_w[j0 * 64 + i4 * 4]);
            }
            __syncthreads();

            #pragma unroll 4
            for (int jj = 0; jj < 64; jj++) {
                float4 l4 = *reinterpret_cast<const float4*>(&s_w[jj * 64 + oq]);
                float4 t4 = *reinterpret_cast<const float4*>(&s_tp[jj * 68 + e0]);
                acc[0][0]+=t4.x*l4.x; acc[0][1]+=t4.x*l4.y; acc[0][2]+=t4.x*l4.z; acc[0][3]+=t4.x*l4.w;
                acc[1][0]+=t4.y*l4.x; acc[1][1]+=t4.y*l4.y; acc[1][2]+=t4.y*l4.z; acc[1][3]+=t4.y*l4.w;
                acc[2][0]+=t4.z*l4.x; acc[2][1]+=t4.z*l4.y; acc[2][2]+=t4.z*l4.z; acc[2][3]+=t4.z*l4.w;
                acc[3][0]+=t4.w*l4.x; acc[3][1]+=t4.w*l4.y; acc[3][2]+=t4.w*l4.z; acc[3][3]+=t4.w*l4.w;
            }
        }

        #pragma unroll
        for (int t = 0; t < 4; t++) {
            float mk = s_misc[(e0+t) * 12 + 10];
            if (mk != 0.0f) {
                int s = __float_as_int(s_misc[(e0+t) * 12 + 9]);
                #pragma unroll
                for (int q = 0; q < 4; q++) atomicAdd(&agg[s * 64 + oq + q], acc[t][q] * mk);
            }
        }
    }
}

// ---------------- h_local + score + sort key ----------------
__global__ __launch_bounds__(256) void k_hlscore(const float* __restrict__ h,
    const float* __restrict__ agg, const float* __restrict__ deg,
    const float* __restrict__ ms_w1, const float* __restrict__ ms_b1,
    const float* __restrict__ ms_w2, const float* __restrict__ ms_b2,
    float* __restrict__ h_local, float* __restrict__ score, unsigned long long* __restrict__ key)
{
    int wid = threadIdx.x >> 6, lane = threadIdx.x & 63;
    int n = blockIdx.x * 4 + wid;
    if (n >= N_) return;
    float d = fmaxf(deg[n], 1.0f);
    float hl = h[n*64 + lane] + agg[n*64 + lane] / d;
    h_local[n*64 + lane] = hl;
    float acc = ms_b1[lane];
    #pragma unroll
    for (int i = 0; i < 16; i++) acc += __shfl(hl, i) * ms_w1[i*64 + lane];
    acc = fmaxf(acc, 0.0f);
    float part = acc * ms_w2[lane];
    #pragma unroll
    for (int off = 32; off > 0; off >>= 1) part += __shfl_xor(part, off);
    if (lane == 0) {
        float s = part + ms_b2[0];
        float sc = 1.0f / (1.0f + expf(-s));
        score[n] = sc;
        key[n] = ((unsigned long long)__float_as_uint(sc) << 32)
               | (unsigned long long)(0xFFFFFFFFu - (unsigned)n);
    }
}

// ---------------- rank counting + (last-done block) selection/scan/compaction (R11-proven) ----------------
__global__ __launch_bounds__(256) void k_rankscan(const unsigned long long* __restrict__ key,
    int* __restrict__ rankcnt, const float* __restrict__ score,
    int* __restrict__ node2m, int* __restrict__ midx, float* __restrict__ m_out,
    unsigned int* __restrict__ done)
{
    int tid = threadIdx.x, lane = tid & 63, wv = tid >> 6;
    {
        int ib = blockIdx.x % 79;
        int seg = blockIdx.x / 79;
        int i = ib * 256 + tid;
        int lo = seg * 1250, hi = lo + 1250;
        unsigned long long my = (i < N_) ? key[i] : ~0ull;
        int cnt = 0;
        #pragma unroll 8
        for (int j = lo; j < hi; j++) cnt += (key[j] > my) ? 1 : 0;
        if (i < N_ && cnt) atomicAdd(&rankcnt[i], cnt);
    }
    __threadfence();
    __syncthreads();
    __shared__ unsigned int s_last;
    if (tid == 0) s_last = (atomicAdd(done, 1u) == (unsigned)gridDim.x - 1u) ? 1u : 0u;
    __syncthreads();
    if (!s_last) return;
    __threadfence();

    // ordered compaction: thread t owns [79t, 79t+79); coherent reads via atomicAdd(p,0)
    const int base = tid * 79;
    unsigned long long m0 = 0ull; unsigned m1 = 0u;
    int csel = 0;
    for (int k = 0; k < 79; k++) {
        int idx = base + k;
        if (idx < N_) {
            int r = atomicAdd(&rankcnt[idx], 0);
            int sel = (r < K_) ? 1 : 0;
            m_out[idx] = sel ? score[idx] : 0.0f;
            if (sel) {
                if (k < 64) m0 |= (1ull << k); else m1 |= (1u << (k - 64));
                csel++;
            }
        }
    }
    __shared__ int wsum[4], wbase[4];
    int v = csel;
    #pragma unroll
    for (int off = 1; off < 64; off <<= 1) {
        int u = __shfl_up(v, off);
        if (lane >= off) v += u;
    }
    if (lane == 63) wsum[wv] = v;
    __syncthreads();
    if (tid == 0) { int run = 0; for (int w = 0; w < 4; w++) { int c = wsum[w]; wbase[w] = run; run += c; } }
    __syncthreads();
    int run = wbase[wv] + v - csel;
    for (int k = 0; k < 79; k++) {
        int idx = base + k;
        if (idx < N_) {
            bool sel = (k < 64) ? ((m0 >> k) & 1ull) : ((m1 >> (k - 64)) & 1u);
            if (sel) { node2m[idx] = run; midx[run] = idx; run++; }
            else node2m[idx] = -1;
        }
    }
}

// ---------------- master gather + q/k proj + exist matrix ----------------
__global__ __launch_bounds__(256) void k_mastex(const int* __restrict__ midx,
    const float* __restrict__ h_local, const float* __restrict__ pos,
    const float* __restrict__ vg_wq, const float* __restrict__ vg_wk,
    const int* __restrict__ src, const int* __restrict__ dst, const int* __restrict__ node2m,
    float* __restrict__ h_m, float* __restrict__ pos_m,
    float* __restrict__ qbuf, float* __restrict__ kbuf,
    int* __restrict__ src_all, int* __restrict__ dst_all,
    float* __restrict__ mask_all, unsigned char* __restrict__ exist)
{
    int b = blockIdx.x;
    if (b < 500) {
        int mi = b * 4 + (threadIdx.x >> 6);
        int lane = threadIdx.x & 63;
        int node = midx[mi];
        h_m[mi*64 + lane] = h_local[node*64 + lane];
        if (lane < 3) pos_m[mi*3 + lane] = pos[node*3 + lane];
        if (lane < 32) {
            int j = lane & 15;
            const float* wm = (lane < 16) ? vg_wq : vg_wk;
            float acc = 0.0f;
            #pragma unroll
            for (int i = 0; i < 16; i++) acc += h_local[node*64 + i] * wm[i*16 + j];
            if (lane < 16) qbuf[mi*16 + j] = acc; else kbuf[mi*16 + j] = acc;
        }
    } else {
        int e = (b - 500) * 256 + threadIdx.x;
        int sm = node2m[src[e]], dm = node2m[dst[e]];
        bool em = (sm >= 0) && (dm >= 0);
        int smc = sm >= 0 ? sm : 0;
        int dmc = dm >= 0 ? dm : 0;
        src_all[e] = smc; dst_all[e] = dmc; mask_all[e] = em ? 1.0f : 0.0f;
        if (em) exist[smc * K_ + dmc] = 1;
    }
}

// ---------------- attention pass 1 (FLAT, R12-proven) ----------------
__global__ __launch_bounds__(256) void k_attn1(const float* __restrict__ qbuf,
    const float* __restrict__ kbuf, const unsigned char* __restrict__ exist,
    float* __restrict__ Av, float* __restrict__ wmax, unsigned int* __restrict__ hist,
    RState* st, unsigned int* __restrict__ done_ctr)
{
    __shared__ unsigned int lh[1024];
    __shared__ unsigned int ha[1024], hb[1024];
    __shared__ unsigned int s_last;
    int tid = threadIdx.x, lane = tid & 63;
    for (int b = tid; b < 1024; b += 256) lh[b] = 0;
    __syncthreads();

    const int stride = gridDim.x * 256;
    for (int flat = blockIdx.x * 256 + tid; flat < NFLAT_; flat += stride) {
        int gi = flat / K_;
        int gj = flat - gi * K_;
        const float4* qp = reinterpret_cast<const float4*>(qbuf + gi * 16);
        const float4* kp = reinterpret_cast<const float4*>(kbuf + gj * 16);
        float dot = 0.0f;
        #pragma unroll
        for (int c4 = 0; c4 < 4; c4++) {
            float4 q4 = qp[c4], k4 = kp[c4];
            dot += q4.x*k4.x + q4.y*k4.y + q4.z*k4.z + q4.w*k4.w;
        }
        float attn = 1.0f / (1.0f + expf(-dot * 0.25f));
        bool ex = (exist[flat] != 0) || (gi == gj);
        bool av = (!ex) && (attn > 0.5f);
        Av[flat] = av ? 1.0f : 0.0f;
        float cv = av ? attn : 0.0f;
        if (av) {
            unsigned bin = (__float_as_uint(attn) - 0x3F000000u) >> 13;
            if (bin > 1023u) bin = 1023u;
            atomicAdd(&lh[bin], 1u);
        }
        float wm = cv;
        #pragma unroll
        for (int off = 32; off > 0; off >>= 1) wm = fmaxf(wm, __shfl_xor(wm, off));
        if (lane == 0) wmax[flat >> 6] = wm;
    }
    __syncthreads();
    for (int b = tid; b < 1024; b += 256) {
        unsigned v = lh[b];
        if (v) atomicAdd(&hist[b], v);
    }
    __syncthreads();
    __threadfence();
    if (tid == 0) s_last = (atomicAdd(done_ctr, 1u) == (unsigned)gridDim.x - 1u) ? 1u : 0u;
    __syncthreads();
    if (!s_last) return;
    __threadfence();
    for (int b = tid; b < 1024; b += 256) ha[b] = atomicAdd(&hist[b], 0u);
    __syncthreads();
    unsigned* srcp = ha; unsigned* dstp = hb;
    for (int off = 1; off < 1024; off <<= 1) {
        for (int b = tid; b < 1024; b += 256)
            dstp[b] = srcp[b] + ((b + off < 1024) ? srcp[b + off] : 0u);
        __syncthreads();
        unsigned* tmp = srcp; srcp = dstp; dstp = tmp;
    }
    unsigned total = srcp[0];
    int R = (total < (unsigned)EV_) ? (int)total : EV_;
    if (tid == 0) {
        st->R = R; st->total = total; st->cand_count = 0; st->sel_count = 0;
        if (R == 0) st->bin_thresh = 1024;
    }
    __syncthreads();
    if (R > 0) {
        for (int b = tid; b < 1024; b += 256) {
            unsigned hi2 = (b == 1023) ? 0u : srcp[b + 1];
            if ((int)srcp[b] >= R && (int)hi2 < R) st->bin_thresh = b;
        }
    }
}

// ---------------- attention pass 2 + (last-done block) radix select + emit ----------------
// cand written with atomicExch (device-scope) so the last block can read coherently.
__global__ __launch_bounds__(256) void k_attn2rs(const float* __restrict__ qbuf,
    const float* __restrict__ kbuf, const unsigned char* __restrict__ exist,
    const float* __restrict__ wmax, RState* st, unsigned long long* __restrict__ cand,
    int* __restrict__ src_all, int* __restrict__ dst_all, float* __restrict__ mask_all,
    unsigned int* __restrict__ done)
{
    __shared__ int wb[4];
    __shared__ int bb;
    __shared__ unsigned int s_last;
    int tid = threadIdx.x, lane = tid & 63, wv = tid >> 6;
    unsigned tbits = 0x3F000000u + ((unsigned)st->bin_thresh << 13);
    const int stride = gridDim.x * 256;

    for (int base = blockIdx.x * 256; base < NFLAT_; base += stride) {
        int flat = base + tid;
        bool wactive = __float_as_uint(wmax[(base + wv * 64) >> 6]) >= tbits;
        bool store = false;
        unsigned long long keyv = 0ull;
        if (wactive) {
            int gi = flat / K_;
            int gj = flat - gi * K_;
            const float4* qp = reinterpret_cast<const float4*>(qbuf + gi * 16);
            const float4* kp = reinterpret_cast<const float4*>(kbuf + gj * 16);
            float dot = 0.0f;
            #pragma unroll
            for (int c4 = 0; c4 < 4; c4++) {
                float4 q4 = qp[c4], k4 = kp[c4];
                dot += q4.x*k4.x + q4.y*k4.y + q4.z*k4.z + q4.w*k4.w;
            }
            float attn = 1.0f / (1.0f + expf(-dot * 0.25f));
            bool ex = (exist[flat] != 0) || (gi == gj);
            store = (!ex) && (attn > 0.5f) && (__float_as_uint(attn) >= tbits);
            keyv = ((unsigned long long)__float_as_uint(attn) << 32)
                 | (unsigned long long)(0xFFFFFFFFu - (unsigned)flat);
        }
        unsigned long long b = __ballot(store);
        int wc = __popcll(b);
        if (lane == 0) wb[wv] = wc;
        __syncthreads();
        if (tid == 0) {
            int s = 0;
            for (int w = 0; w < 4; w++) { int cc2 = wb[w]; wb[w] = s; s += cc2; }
            bb = s ? (int)atomicAdd(&st->cand_count, (unsigned)s) : 0;
        }
        __syncthreads();
        if (store) {
            int slot = bb + wb[wv] + __popcll(b & ((1ull << lane) - 1ull));
            atomicExch(&cand[slot], keyv);          // device-coherent write
        }
        __syncthreads();
    }

    // ---- last-done block: radix threshold + tie resolution + emit ----
    __threadfence();
    __syncthreads();
    if (tid == 0) s_last = (atomicAdd(done, 1u) == (unsigned)gridDim.x - 1u) ? 1u : 0u;
    __syncthreads();
    if (!s_last) return;
    __threadfence();

    __shared__ unsigned int lh2[256];
    __shared__ unsigned int suf[256];
    __shared__ unsigned int s_tie[8192];
    __shared__ unsigned int scal[4];       // pref, R, tiecnt, cfth
    int n = (int)atomicAdd(&st->cand_count, 0u);
    int R = st->R;                          // written by prior kernel (boundary-coherent)
    if (tid == 0) { scal[0] = 0x3F000000u; scal[1] = (unsigned)R; scal[2] = 0; scal[3] = 0; }
    __syncthreads();

    unsigned long long T;
    if (R > 0) {
        for (int pss = 0; pss < 3; pss++) {
            lh2[tid] = 0;
            __syncthreads();
            unsigned pref = scal[0];
            int sh_d = 16 - 8 * pss;
            unsigned pm = 0xFFFFFFFFu << (sh_d + 8);
            for (int i = tid; i < n; i += 256) {
                unsigned long long kv = atomicAdd(&cand[i], 0ull);   // coherent read
                unsigned a = (unsigned)(kv >> 32);
                if ((a & pm) == (pref & pm))
                    atomicAdd(&lh2[(a >> sh_d) & 255u], 1u);
            }
            __syncthreads();
            suf[tid] = lh2[tid];
            __syncthreads();
            for (int off = 1; off < 256; off <<= 1) {
                unsigned v = (tid + off < 256) ? suf[tid + off] : 0u;
                __syncthreads();
                suf[tid] += v;
                __syncthreads();
            }
            {
                unsigned Rc = scal[1];
                unsigned hi2 = (tid == 255) ? 0u : suf[tid + 1];
                if (suf[tid] >= Rc && hi2 < Rc) {
                    scal[0] = pref | ((unsigned)tid << sh_d);
                    scal[1] = Rc - hi2;
                }
            }
            __syncthreads();
        }
        unsigned Ta = scal[0];
        unsigned Rrem = scal[1];
        for (int i = tid; i < n; i += 256) {
            unsigned long long kv = atomicAdd(&cand[i], 0ull);
            if ((unsigned)(kv >> 32) == Ta) {
                unsigned pos = atomicAdd(&scal[2], 1u);
                if (pos < 8192u) s_tie[pos] = (unsigned)(kv & 0xFFFFFFFFull);
            }
        }
        __syncthreads();
        unsigned Cq = scal[2]; if (Cq > 8192u) Cq = 8192u;
        if (Rrem >= 1u && Rrem < Cq) {
            for (int i = tid; i < (int)Cq; i += 256) {
                unsigned me = s_tie[i];
                unsigned r = 0;
                for (int j = 0; j < (int)Cq; j++) r += (s_tie[j] > me) ? 1u : 0u;
                if (r == Rrem - 1u) scal[3] = me;
            }
        }
        __syncthreads();
        T = ((unsigned long long)Ta << 32) | (unsigned long long)scal[3];
    } else {
        T = ~0ull;
    }

    for (int i0 = 0; i0 < n; i0 += 256) {
        int i = i0 + tid;
        unsigned long long kv = (i < n) ? atomicAdd(&cand[i], 0ull) : 0ull;
        bool sel = (i < n) && (kv >= T);
        unsigned long long b = __ballot(sel);
        int wc = __popcll(b);
        int basep = 0;
        if (lane == 0 && wc) basep = (int)atomicAdd(&st->sel_count, (unsigned)wc);
        basep = __shfl(basep, 0);
        if (sel) {
            int slot = basep + __popcll(b & ((1ull << lane) - 1ull));
            if (slot < EV_) {
                unsigned flat = 0xFFFFFFFFu - (unsigned)(kv & 0xFFFFFFFFull);
                src_all[E_ + slot] = (int)(flat / (unsigned)K_);
                dst_all[E_ + slot] = (int)(flat % (unsigned)K_);
                mask_all[E_ + slot] = 1.0f;
            }
        }
    }
}

// ---------------- final mixing + pos copy ----------------
__global__ void k_finalpos(const float* __restrict__ h_local, const int* __restrict__ node2m,
    const float* __restrict__ aggm, const float* __restrict__ degm, const float* __restrict__ h_m,
    const float* __restrict__ m_out, const float* __restrict__ pos,
    float* __restrict__ out_h, float* __restrict__ out_pos)
{
    int idx = blockIdx.x * 256 + threadIdx.x;
    if (idx < N_ * 3) out_pos[idx] = pos[idx];
    if (idx >= N_ * C_) return;
    int i = idx >> 6, c = idx & 63;
    float mval = m_out[i];
    int mi = node2m[i];
    float hh = 0.0f;
    if (mi >= 0) hh = aggm[mi*64 + c] / fmaxf(degm[mi], 1.0f) + h_m[mi*64 + c];
    out_h[idx] = (1.0f - mval) * h_local[idx] + mval * hh;
}

// ---------------- launch ----------------
extern "C" void kernel_launch(void* const* d_in, const int* in_sizes, int n_in,
                              void* d_out, int out_size, void* d_ws, size_t ws_size,
                              hipStream_t stream)
{
    (void)in_sizes; (void)n_in; (void)out_size; (void)ws_size;
    const float* h     = (const float*)d_in[0];
    const float* pos   = (const float*)d_in[1];
    const int*   eidx  = (const int*)d_in[2];
    const float* fc_w1 = (const float*)d_in[3];
    const float* fc_b1 = (const float*)d_in[4];
    const float* fc_w2 = (const float*)d_in[5];
    const float* fc_b2 = (const float*)d_in[6];
    const float* lin_w = (const float*)d_in[7];
    const float* ms_w1 = (const float*)d_in[8];
    const float* ms_b1 = (const float*)d_in[9];
    const float* ms_w2 = (const float*)d_in[10];
    const float* ms_b2 = (const float*)d_in[11];
    const float* vg_wq = (const float*)d_in[12];
    const float* vg_wk = (const float*)d_in[13];

    char* ws = (char*)d_ws;
    float* agg     = (float*)(ws + OFF_AGG);
    float* deg     = (float*)(ws + OFF_DEG);
    float* aggm    = (float*)(ws + OFF_AGGM);
    float* degm    = (float*)(ws + OFF_DEGM);
    int*   rankcnt = (int*)(ws + OFF_RANK);
    float* mask_all = (float*)(ws + OFF_MASKA);
    unsigned char* exist = (unsigned char*)(ws + OFF_EXIST);
    unsigned int* hist = (unsigned int*)(ws + OFF_HIST);
    RState* st     = (RState*)(ws + OFF_STATE);
    unsigned int* cnt0 = (unsigned int*)(ws + OFF_STATE + 64);
    unsigned int* cnt1 = (unsigned int*)(ws + OFF_STATE + 68);
    int*   w0nz    = (int*)(ws + OFF_STATE + 72);
    unsigned int* done_a1 = (unsigned int*)(ws + OFF_STATE + 76);
    unsigned int* done_rk = (unsigned int*)(ws + OFF_STATE + 80);
    unsigned int* done_a2 = (unsigned int*)(ws + OFF_STATE + 84);
    float* h_local = (float*)(ws + OFF_HLOCAL);
    unsigned long long* key = (unsigned long long*)(ws + OFF_KEY);
    float* score   = (float*)(ws + OFF_SCORE);
    int*   node2m  = (int*)(ws + OFF_N2M);
    int*   midx    = (int*)(ws + OFF_MIDX);
    float* h_m     = (float*)(ws + OFF_HM);
    float* pos_m   = (float*)(ws + OFF_POSM);
    float* qbuf    = (float*)(ws + OFF_Q);
    float* kbuf    = (float*)(ws + OFF_KBUF);
    int*   src_all = (int*)(ws + OFF_SRCA);
    int*   dst_all = (int*)(ws + OFF_DSTA);
    float* wmax    = (float*)(ws + OFF_WMAX);
    unsigned long long* cand = (unsigned long long*)(ws + OFF_CAND);
    float* edata   = (float*)(ws + OFF_CAND);        // overlays cand (stream-ordered: safe)

    float* out_h   = (float*)d_out;
    float* out_pos = out_h + (size_t)N_ * C_;
    float* out_av  = out_pos + (size_t)N_ * 3;
    float* out_m   = out_av + (size_t)K_ * K_;

    k_init<<<768, 256, 0, stream>>>(fc_b1, fc_w2, fc_b2, ws);

    // ---- conv 1 on full graph ----
    k_prep<<<E_ / 256, 256, 0, stream>>>(E_, eidx, eidx + E_, nullptr, pos, w0nz, deg, edata, cnt0);
    k_convg<<<768, 256, 0, stream>>>(cnt0, edata, h, fc_w1, fc_b1, fc_w2, fc_b2, lin_w, agg);

    k_hlscore<<<(N_ + 3) / 4, 256, 0, stream>>>(h, agg, deg, ms_w1, ms_b1, ms_w2, ms_b2,
                                                h_local, score, key);

    k_rankscan<<<79 * 16, 256, 0, stream>>>(key, rankcnt, score, node2m, midx, out_m, done_rk);

    k_mastex<<<500 + E_ / 256, 256, 0, stream>>>(midx, h_local, pos, vg_wq, vg_wk,
        eidx, eidx + E_, node2m, h_m, pos_m, qbuf, kbuf, src_all, dst_all, mask_all, exist);

    // ---- virtual edge selection (flat attention; radix+emit fused into attn2) ----
    k_attn1<<<1024, 256, 0, stream>>>(qbuf, kbuf, exist, out_av, wmax, hist, st, done_a1);
    k_attn2rs<<<1024, 256, 0, stream>>>(qbuf, kbuf, exist, wmax, st, cand,
                                        src_all, dst_all, mask_all, done_a2);

    // ---- conv 2 on master graph ----
    k_prep<<<EALL_ / 256, 256, 0, stream>>>(EALL_, src_all, dst_all, mask_all, pos_m, w0nz,
                                            degm, edata, cnt1);
    k_convg<<<768, 256, 0, stream>>>(cnt1, edata, h_m, fc_w1, fc_b1, fc_w2, fc_b2, lin_w, aggm);

    k_finalpos<<<(N_ * C_ + 255) / 256, 256, 0, stream>>>(h_local, node2m, aggm, degm, h_m,
                                                          out_m, pos, out_h, out_pos);
}

// Round 14
// 710.470 us; speedup vs baseline: 1.3794x; 1.3794x over previous
//
#include <hip/hip_runtime.h>
#include <stdint.h>

// ---------------- problem constants ----------------
constexpr int N_   = 20000;
constexpr int E_   = 160000;
constexpr int C_   = 64;
constexpr int K_   = 2000;
constexpr int EV_  = 32000;
constexpr int EALL_ = E_ + EV_;          // 192000
constexpr int CSH_ = 576;                // C*SH
constexpr int TB_  = 64;                 // edges per block in batched conv
constexpr int NFLAT_ = K_ * K_;          // 4,000,000

// ---------------- workspace layout (bytes) ----------------
constexpr size_t OFF_AGG    = 0;                  // N*C f32
constexpr size_t OFF_DEG    = 5120000;            // N f32
constexpr size_t OFF_AGGM   = 5200000;            // K*C f32
constexpr size_t OFF_DEGM   = 5712000;            // K f32
constexpr size_t OFF_RANK   = 5720000;            // N i32
constexpr size_t OFF_MASKA  = 5800000;            // EALL f32
constexpr size_t OFF_EXIST  = 6568000;            // K*K u8
constexpr size_t OFF_HIST   = 10568000;           // 1024 u32
constexpr size_t OFF_STATE  = 10572096;           // RState + counters 256  (zeroed by k_init)
// [ non-zero region ]
constexpr size_t OFF_HLOCAL = 10572352;           // N*C f32
constexpr size_t OFF_KEY    = 15692352;           // N u64
constexpr size_t OFF_SCORE  = 15852352;           // N f32
constexpr size_t OFF_N2M    = 15932352;           // N i32
constexpr size_t OFF_MIDX   = 16012352;           // K i32
constexpr size_t OFF_HM     = 16020352;           // K*C f32
constexpr size_t OFF_POSM   = 16532352;           // K*3 f32
constexpr size_t OFF_Q      = 16556352;           // K*16 f32
constexpr size_t OFF_KBUF   = 16684352;           // K*16 f32
constexpr size_t OFF_SRCA   = 16812352;           // EALL i32
constexpr size_t OFF_DSTA   = 17580352;           // EALL i32
constexpr size_t OFF_WMAX   = 18348352;           // 62500 f32 per-wave attn max (250,000 B)
constexpr size_t OFF_CAND   = 18598400;           // cand keys / edata overlay
// total used ~38.7 MB

struct RState {
    unsigned long long prefix;
    int R;
    unsigned int cand_count;
    unsigned int sel_count;
    int bin_thresh;
    unsigned int total;
    unsigned int pad;
};
// state area: RState at +0, cnt0 +64, cnt1 +68, w0nz +72, done_a1 +76

// ---------------- k_init: zero workspace + (last block) state zero + w0nz ----------------
__global__ __launch_bounds__(256) void k_init(const float* __restrict__ fc_b1,
    const float* __restrict__ fc_w2, const float* __restrict__ fc_b2, char* __restrict__ ws)
{
    float4 zero4 = make_float4(0.f, 0.f, 0.f, 0.f);
    float4* z = (float4*)ws;
    int nz4 = (int)(OFF_STATE / 16);
    for (int i = blockIdx.x * 256 + threadIdx.x; i < nz4; i += gridDim.x * 256) z[i] = zero4;
    if (blockIdx.x == gridDim.x - 1) {
        __shared__ float hid0[64];
        __shared__ int nz;
        int t = threadIdx.x;
        float4* zs = (float4*)(ws + OFF_STATE);
        if (t < 16) zs[t] = zero4;
        if (t == 0) nz = 0;
        if (t < 64) hid0[t] = fmaxf(fc_b1[t], 0.0f);
        __syncthreads();
        for (int j = t; j < CSH_; j += 256) {
            float acc = fc_b2[j];
            for (int k = 0; k < 64; k++) acc += hid0[k] * fc_w2[k * CSH_ + j];
            if (acc != 0.0f) atomicOr(&nz, 1);
        }
        __syncthreads();
        if (t == 0) *(int*)(ws + OFF_STATE + 72) = nz;
    }
}

// ---------------- edge prep: geometry + bessel, deg atomics, compact contributing edges ----------------
// edata layout per edge (20 f32): ef[8], sh[9], src(bits), dst(bits), msk
__global__ __launch_bounds__(256) void k_prep(
    int n_edges, const int* __restrict__ src, const int* __restrict__ dst,
    const float* __restrict__ mask, const float* __restrict__ posn,
    const int* __restrict__ w0nz, float* __restrict__ deg,
    float* __restrict__ edata, unsigned int* __restrict__ cnt)
{
    int e = blockIdx.x * 256 + threadIdx.x;
    bool valid = e < n_edges;
    int s_i = 0, d_i = 0; float msk = 0.0f;
    if (valid) {
        msk = mask ? mask[e] : 1.0f;
        if (msk != 0.0f) { s_i = src[e]; d_i = dst[e]; }
    }
    bool active = valid && (msk != 0.0f);

    float vx = 0.f, vy = 0.f, vz = 0.f;
    if (active) {
        vx = posn[s_i*3+0] - posn[d_i*3+0];
        vy = posn[s_i*3+1] - posn[d_i*3+1];
        vz = posn[s_i*3+2] - posn[d_i*3+2];
    }
    float r = sqrtf(vx*vx + vy*vy + vz*vz + 1e-12f);
    float invr = 1.0f / r;
    float x = vx*invr, y = vy*invr, z = vz*invr;
    const float s3 = 1.7320508075688772f, s15 = 3.872983346207417f, s5 = 2.23606797749979f;
    float sh[9];
    sh[0] = 1.0f; sh[1] = s3*x; sh[2] = s3*y; sh[3] = s3*z;
    sh[4] = s15*x*y; sh[5] = s15*y*z; sh[6] = 0.5f*s5*(3.0f*z*z - 1.0f);
    sh[7] = s15*x*z; sh[8] = 0.5f*s15*(x*x - y*y);

    float u = r * 0.2f; u = u > 1.0f ? 1.0f : u;
    float u2 = u*u, u6 = u2*u2*u2, u7 = u6*u, u8 = u7*u;
    float env = 1.0f - 28.0f*u6 + 48.0f*u7 - 21.0f*u8;
    float rc = r > 1e-9f ? r : 1e-9f;
    const float bpref = 0.6324555320336759f;      // sqrt(2/5)
    const float PIov5 = 0.6283185307179586f;
    float ef[8];
    #pragma unroll
    for (int n = 0; n < 8; n++)
        ef[n] = bpref * sinf(PIov5 * r * (float)(n + 1)) / rc * env;

    if (active) atomicAdd(&deg[s_i], msk);

    bool contrib = active && !((env == 0.0f) && (*w0nz == 0));
    int lane = threadIdx.x & 63;
    unsigned long long b = __ballot(contrib);
    int wc = __popcll(b);
    int base = 0;
    if (lane == 0 && wc) base = (int)atomicAdd(cnt, (unsigned)wc);
    base = __shfl(base, 0);
    if (contrib) {
        int slot = base + __popcll(b & ((1ull << lane) - 1ull));
        float* p = edata + (size_t)slot * 20;
        #pragma unroll
        for (int n = 0; n < 8; n++) p[n] = ef[n];
        #pragma unroll
        for (int t = 0; t < 9; t++) p[8+t] = sh[t];
        p[17] = __int_as_float(s_i);
        p[18] = __int_as_float(d_i);
        p[19] = msk;
    }
}

// ---------------- batched conv GEMM: 64 edges/block, thread = 4 edges x 4 outputs ----------------
__global__ __launch_bounds__(256, 3) void k_convg(
    const unsigned int* __restrict__ cnt, const float* __restrict__ edata,
    const float* __restrict__ hn,
    const float* __restrict__ fc_w1, const float* __restrict__ fc_b1,
    const float* __restrict__ fc_w2, const float* __restrict__ fc_b2,
    const float* __restrict__ lin_w, float* __restrict__ agg)
{
    __shared__ float s_misc[TB_ * 12];                 // sh[9], src, msk, dst
    __shared__ __align__(16) float s_hid[64 * 64];     // [k][e]
    __shared__ __align__(16) float s_tp[64 * 68];      // [j_local][e], stride 68
    __shared__ __align__(16) float s_w[4096];          // w2 chunk, then lin_w chunk

    const int tid = threadIdx.x;
    const int oq = (tid & 15) * 4;                     // output/j quad (chunk-local)
    const int e0 = (tid >> 4) * 4;                     // this thread's 4 edges

    const int nheavy = (int)*cnt;
    const int nblk = (nheavy + TB_ - 1) / TB_;

    for (int blk = blockIdx.x; blk < nblk; blk += gridDim.x) {
        const int ebase = blk * TB_;
        int nE = nheavy - ebase; if (nE > TB_) nE = TB_;

        __syncthreads();    // prior tile fully consumed
        for (int idx = tid; idx < TB_ * 12; idx += 256) {
            int e = idx / 12, f = idx - 12 * e;
            float v = 0.0f;
            if (e < nE) {
                const float* p = edata + (size_t)(ebase + e) * 20;
                v = (f < 9) ? p[8 + f] : (f == 9) ? p[17] : (f == 10) ? p[19] : p[18];
            }
            s_misc[idx] = v;
        }
        for (int idx = tid; idx < TB_ * 64; idx += 256) {
            int k = idx >> 6, e = idx & 63;
            float hv = 0.0f;
            if (e < nE) {
                const float* p = edata + (size_t)(ebase + e) * 20;
                float acc = fc_b1[k];
                #pragma unroll
                for (int n = 0; n < 8; n++) acc += p[n] * fc_w1[n * 64 + k];
                hv = fmaxf(acc, 0.0f);
            }
            s_hid[k * 64 + e] = hv;
        }
        float acc[4][4] = {{0,0,0,0},{0,0,0,0},{0,0,0,0},{0,0,0,0}};
        __syncthreads();

        const int d0 = __float_as_int(s_misc[(e0+0) * 12 + 11]);
        const int d1 = __float_as_int(s_misc[(e0+1) * 12 + 11]);
        const int d2 = __float_as_int(s_misc[(e0+2) * 12 + 11]);
        const int d3 = __float_as_int(s_misc[(e0+3) * 12 + 11]);

        for (int cj = 0; cj < 9; cj++) {
            const int j0 = cj * 64;
            if (cj) __syncthreads();
            for (int i4 = tid; i4 < 1024; i4 += 256) {
                int k = i4 >> 4, q4 = (i4 & 15) * 4;
                *reinterpret_cast<float4*>(&s_w[k * 64 + q4]) =
                    *reinterpret_cast<const float4*>(&fc_w2[k * CSH_ + j0 + q4]);
            }
            __syncthreads();

            const int jb = j0 + oq;
            const int c0 = jb / 9, c1 = (jb + 3) / 9;
            float hA0 = hn[d0 * 64 + c0], hB0 = hn[d0 * 64 + c1];
            float hA1 = hn[d1 * 64 + c0], hB1 = hn[d1 * 64 + c1];
            float hA2 = hn[d2 * 64 + c0], hB2 = hn[d2 * 64 + c1];
            float hA3 = hn[d3 * 64 + c0], hB3 = hn[d3 * 64 + c1];

            float a[4][4];
            #pragma unroll
            for (int q = 0; q < 4; q++) {
                float b = fc_b2[jb + q];
                a[0][q]=b; a[1][q]=b; a[2][q]=b; a[3][q]=b;
            }
            #pragma unroll 4
            for (int k = 0; k < 64; k++) {
                float4 w4 = *reinterpret_cast<const float4*>(&s_w[k * 64 + oq]);
                float4 h4 = *reinterpret_cast<const float4*>(&s_hid[k * 64 + e0]);
                a[0][0]+=h4.x*w4.x; a[0][1]+=h4.x*w4.y; a[0][2]+=h4.x*w4.z; a[0][3]+=h4.x*w4.w;
                a[1][0]+=h4.y*w4.x; a[1][1]+=h4.y*w4.y; a[1][2]+=h4.y*w4.z; a[1][3]+=h4.y*w4.w;
                a[2][0]+=h4.z*w4.x; a[2][1]+=h4.z*w4.y; a[2][2]+=h4.z*w4.z; a[2][3]+=h4.z*w4.w;
                a[3][0]+=h4.w*w4.x; a[3][1]+=h4.w*w4.y; a[3][2]+=h4.w*w4.z; a[3][3]+=h4.w*w4.w;
            }
            // tp[j_local][e]; CHUNK-LOCAL row (oq+q)
            #pragma unroll
            for (int q = 0; q < 4; q++) {
                int j = jb + q; int cc = j / 9; int si = j - 9 * cc;
                float4 tpv;
                tpv.x = (cc == c0 ? hA0 : hB0) * s_misc[(e0+0) * 12 + si] * a[0][q];
                tpv.y = (cc == c0 ? hA1 : hB1) * s_misc[(e0+1) * 12 + si] * a[1][q];
                tpv.z = (cc == c0 ? hA2 : hB2) * s_misc[(e0+2) * 12 + si] * a[2][q];
                tpv.w = (cc == c0 ? hA3 : hB3) * s_misc[(e0+3) * 12 + si] * a[3][q];
                *reinterpret_cast<float4*>(&s_tp[(oq + q) * 68 + e0]) = tpv;
            }
            __syncthreads();

            for (int i4 = tid; i4 < 1024; i4 += 256) {
                *reinterpret_cast<float4*>(&s_w[i4 * 4]) =
                    *reinterpret_cast<const float4*>(&lin_w[j0 * 64 + i4 * 4]);
            }
            __syncthreads();

            #pragma unroll 4
            for (int jj = 0; jj < 64; jj++) {
                float4 l4 = *reinterpret_cast<const float4*>(&s_w[jj * 64 + oq]);
                float4 t4 = *reinterpret_cast<const float4*>(&s_tp[jj * 68 + e0]);
                acc[0][0]+=t4.x*l4.x; acc[0][1]+=t4.x*l4.y; acc[0][2]+=t4.x*l4.z; acc[0][3]+=t4.x*l4.w;
                acc[1][0]+=t4.y*l4.x; acc[1][1]+=t4.y*l4.y; acc[1][2]+=t4.y*l4.z; acc[1][3]+=t4.y*l4.w;
                acc[2][0]+=t4.z*l4.x; acc[2][1]+=t4.z*l4.y; acc[2][2]+=t4.z*l4.z; acc[2][3]+=t4.z*l4.w;
                acc[3][0]+=t4.w*l4.x; acc[3][1]+=t4.w*l4.y; acc[3][2]+=t4.w*l4.z; acc[3][3]+=t4.w*l4.w;
            }
        }

        #pragma unroll
        for (int t = 0; t < 4; t++) {
            float mk = s_misc[(e0+t) * 12 + 10];
            if (mk != 0.0f) {
                int s = __float_as_int(s_misc[(e0+t) * 12 + 9]);
                #pragma unroll
                for (int q = 0; q < 4; q++) atomicAdd(&agg[s * 64 + oq + q], acc[t][q] * mk);
            }
        }
    }
}

// ---------------- h_local + score + sort key (merged) ----------------
__global__ __launch_bounds__(256) void k_hlscore(const float* __restrict__ h,
    const float* __restrict__ agg, const float* __restrict__ deg,
    const float* __restrict__ ms_w1, const float* __restrict__ ms_b1,
    const float* __restrict__ ms_w2, const float* __restrict__ ms_b2,
    float* __restrict__ h_local, float* __restrict__ score, unsigned long long* __restrict__ key)
{
    int wid = threadIdx.x >> 6, lane = threadIdx.x & 63;
    int n = blockIdx.x * 4 + wid;
    if (n >= N_) return;
    float d = fmaxf(deg[n], 1.0f);
    float hl = h[n*64 + lane] + agg[n*64 + lane] / d;
    h_local[n*64 + lane] = hl;
    float acc = ms_b1[lane];
    #pragma unroll
    for (int i = 0; i < 16; i++) acc += __shfl(hl, i) * ms_w1[i*64 + lane];
    acc = fmaxf(acc, 0.0f);
    float part = acc * ms_w2[lane];
    #pragma unroll
    for (int off = 32; off > 0; off >>= 1) part += __shfl_xor(part, off);
    if (lane == 0) {
        float s = part + ms_b2[0];
        float sc = 1.0f / (1.0f + expf(-s));
        score[n] = sc;
        key[n] = ((unsigned long long)__float_as_uint(sc) << 32)
               | (unsigned long long)(0xFFFFFFFFu - (unsigned)n);
    }
}

// ---------------- exact top-K rank counting: wave-uniform global reads ----------------
__global__ __launch_bounds__(256) void k_rank(const unsigned long long* __restrict__ key,
                                              int* __restrict__ rankcnt)
{
    int i = blockIdx.x * 256 + threadIdx.x;
    int seg = blockIdx.y;
    int lo = seg * 1250, hi = lo + 1250;
    unsigned long long my = (i < N_) ? key[i] : ~0ull;
    int cnt = 0;
    #pragma unroll 8
    for (int j = lo; j < hi; j++) cnt += (key[j] > my) ? 1 : 0;
    if (i < N_ && cnt) atomicAdd(&rankcnt[i], cnt);
}

// ---------------- selection + ordered compaction, chunked coalesced block scan ----------------
__global__ __launch_bounds__(1024) void k_scanfin(const int* __restrict__ rankcnt,
    const float* __restrict__ score, int* __restrict__ node2m, int* __restrict__ midx,
    float* __restrict__ m_out)
{
    __shared__ int wsum[16];
    __shared__ int wbase[16];
    __shared__ int s_base;
    int tid = threadIdx.x, lane = tid & 63, wv = tid >> 6;
    if (tid == 0) s_base = 0;
    __syncthreads();
    for (int c = 0; c < 20; c++) {
        int idx = c * 1024 + tid;
        int sel = 0;
        if (idx < N_) {
            sel = (rankcnt[idx] < K_) ? 1 : 0;
            m_out[idx] = sel ? score[idx] : 0.0f;
        }
        int v = sel;
        #pragma unroll
        for (int off = 1; off < 64; off <<= 1) {
            int u = __shfl_up(v, off);
            if (lane >= off) v += u;
        }
        if (lane == 63) wsum[wv] = v;
        __syncthreads();
        if (tid == 0) {
            int runb = s_base;
            for (int w = 0; w < 16; w++) { wbase[w] = runb; runb += wsum[w]; }
            s_base = runb;
        }
        __syncthreads();
        if (idx < N_) {
            if (sel) { int rk = wbase[wv] + v - 1; node2m[idx] = rk; midx[rk] = idx; }
            else node2m[idx] = -1;
        }
    }
}

// ---------------- master gather + q/k proj + exist matrix (merged) ----------------
__global__ __launch_bounds__(256) void k_mastex(const int* __restrict__ midx,
    const float* __restrict__ h_local, const float* __restrict__ pos,
    const float* __restrict__ vg_wq, const float* __restrict__ vg_wk,
    const int* __restrict__ src, const int* __restrict__ dst, const int* __restrict__ node2m,
    float* __restrict__ h_m, float* __restrict__ pos_m,
    float* __restrict__ qbuf, float* __restrict__ kbuf,
    int* __restrict__ src_all, int* __restrict__ dst_all,
    float* __restrict__ mask_all, unsigned char* __restrict__ exist)
{
    int b = blockIdx.x;
    if (b < 500) {
        int mi = b * 4 + (threadIdx.x >> 6);
        int lane = threadIdx.x & 63;
        int node = midx[mi];
        h_m[mi*64 + lane] = h_local[node*64 + lane];
        if (lane < 3) pos_m[mi*3 + lane] = pos[node*3 + lane];
        if (lane < 32) {
            int j = lane & 15;
            const float* wm = (lane < 16) ? vg_wq : vg_wk;
            float acc = 0.0f;
            #pragma unroll
            for (int i = 0; i < 16; i++) acc += h_local[node*64 + i] * wm[i*16 + j];
            if (lane < 16) qbuf[mi*16 + j] = acc; else kbuf[mi*16 + j] = acc;
        }
    } else {
        int e = (b - 500) * 256 + threadIdx.x;   // covers exactly E_
        int sm = node2m[src[e]], dm = node2m[dst[e]];
        bool em = (sm >= 0) && (dm >= 0);
        int smc = sm >= 0 ? sm : 0;
        int dmc = dm >= 0 ? dm : 0;
        src_all[e] = smc; dst_all[e] = dmc; mask_all[e] = em ? 1.0f : 0.0f;
        if (em) exist[smc * K_ + dmc] = 1;
    }
}

// ---------------- attention pass 1 (FLAT): thread-per-element, no block barriers in loop ----------------
__global__ __launch_bounds__(256) void k_attn1(const float* __restrict__ qbuf,
    const float* __restrict__ kbuf, const unsigned char* __restrict__ exist,
    float* __restrict__ Av, float* __restrict__ wmax, unsigned int* __restrict__ hist,
    RState* st, unsigned int* __restrict__ done_ctr)
{
    __shared__ unsigned int lh[1024];
    __shared__ unsigned int ha[1024], hb[1024];
    __shared__ unsigned int s_last;
    int tid = threadIdx.x, lane = tid & 63;
    for (int b = tid; b < 1024; b += 256) lh[b] = 0;
    __syncthreads();

    const int stride = gridDim.x * 256;
    for (int flat = blockIdx.x * 256 + tid; flat < NFLAT_; flat += stride) {
        int gi = flat / K_;
        int gj = flat - gi * K_;
        const float4* qp = reinterpret_cast<const float4*>(qbuf + gi * 16);
        const float4* kp = reinterpret_cast<const float4*>(kbuf + gj * 16);
        float dot = 0.0f;
        #pragma unroll
        for (int c4 = 0; c4 < 4; c4++) {
            float4 q4 = qp[c4], k4 = kp[c4];
            dot += q4.x*k4.x + q4.y*k4.y + q4.z*k4.z + q4.w*k4.w;
        }
        float attn = 1.0f / (1.0f + expf(-dot * 0.25f));
        bool ex = (exist[flat] != 0) || (gi == gj);
        bool av = (!ex) && (attn > 0.5f);
        Av[flat] = av ? 1.0f : 0.0f;
        float cv = av ? attn : 0.0f;
        if (av) {
            unsigned bin = (__float_as_uint(attn) - 0x3F000000u) >> 13;
            if (bin > 1023u) bin = 1023u;
            atomicAdd(&lh[bin], 1u);
        }
        float wm = cv;
        #pragma unroll
        for (int off = 32; off > 0; off >>= 1) wm = fmaxf(wm, __shfl_xor(wm, off));
        if (lane == 0) wmax[flat >> 6] = wm;     // flat of lane0 is 64-aligned
    }
    __syncthreads();
    for (int b = tid; b < 1024; b += 256) {
        unsigned v = lh[b];
        if (v) atomicAdd(&hist[b], v);
    }
    // last-done block picks the bin threshold
    __syncthreads();
    __threadfence();
    if (tid == 0) s_last = (atomicAdd(done_ctr, 1u) == (unsigned)gridDim.x - 1u) ? 1u : 0u;
    __syncthreads();
    if (!s_last) return;
    __threadfence();
    for (int b = tid; b < 1024; b += 256) ha[b] = atomicAdd(&hist[b], 0u);   // coherent read
    __syncthreads();
    unsigned* srcp = ha; unsigned* dstp = hb;
    for (int off = 1; off < 1024; off <<= 1) {
        for (int b = tid; b < 1024; b += 256)
            dstp[b] = srcp[b] + ((b + off < 1024) ? srcp[b + off] : 0u);
        __syncthreads();
        unsigned* tmp = srcp; srcp = dstp; dstp = tmp;
    }
    unsigned total = srcp[0];
    int R = (total < (unsigned)EV_) ? (int)total : EV_;
    if (tid == 0) {
        st->R = R; st->total = total; st->cand_count = 0; st->sel_count = 0;
        if (R == 0) st->bin_thresh = 1024;
    }
    __syncthreads();
    if (R > 0) {
        for (int b = tid; b < 1024; b += 256) {
            unsigned hi2 = (b == 1023) ? 0u : srcp[b + 1];
            if ((int)srcp[b] >= R && (int)hi2 < R) st->bin_thresh = b;
        }
    }
}

// ---------------- attention pass 2 (FLAT): wave-granular skip + block-aggregated store ----------------
__global__ __launch_bounds__(256) void k_attn2(const float* __restrict__ qbuf,
    const float* __restrict__ kbuf, const unsigned char* __restrict__ exist,
    const float* __restrict__ wmax, RState* st, unsigned long long* __restrict__ cand)
{
    __shared__ int wb[4];
    __shared__ int bb;
    int tid = threadIdx.x, lane = tid & 63, wv = tid >> 6;
    unsigned tbits = 0x3F000000u + ((unsigned)st->bin_thresh << 13);
    const int stride = gridDim.x * 256;

    for (int base = blockIdx.x * 256; base < NFLAT_; base += stride) {
        int flat = base + tid;
        bool wactive = __float_as_uint(wmax[(base + wv * 64) >> 6]) >= tbits;   // wave-uniform
        bool store = false;
        unsigned long long keyv = 0ull;
        if (wactive) {
            int gi = flat / K_;
            int gj = flat - gi * K_;
            const float4* qp = reinterpret_cast<const float4*>(qbuf + gi * 16);
            const float4* kp = reinterpret_cast<const float4*>(kbuf + gj * 16);
            float dot = 0.0f;
            #pragma unroll
            for (int c4 = 0; c4 < 4; c4++) {
                float4 q4 = qp[c4], k4 = kp[c4];
                dot += q4.x*k4.x + q4.y*k4.y + q4.z*k4.z + q4.w*k4.w;
            }
            float attn = 1.0f / (1.0f + expf(-dot * 0.25f));
            bool ex = (exist[flat] != 0) || (gi == gj);
            store = (!ex) && (attn > 0.5f) && (__float_as_uint(attn) >= tbits);
            keyv = ((unsigned long long)__float_as_uint(attn) << 32)
                 | (unsigned long long)(0xFFFFFFFFu - (unsigned)flat);
        }
        unsigned long long b = __ballot(store);
        int wc = __popcll(b);
        if (lane == 0) wb[wv] = wc;
        __syncthreads();
        if (tid == 0) {
            int s = 0;
            for (int w = 0; w < 4; w++) { int cc2 = wb[w]; wb[w] = s; s += cc2; }
            bb = s ? (int)atomicAdd(&st->cand_count, (unsigned)s) : 0;
        }
        __syncthreads();
        if (store) {
            int slot = bb + wb[wv] + __popcll(b & ((1ull << lane) - 1ull));
            cand[slot] = keyv;
        }
        __syncthreads();   // wb/bb reused next iteration
    }
}

// ---------------- radix select: 3 passes over attn bytes + tie resolution + emit ----------------
__global__ __launch_bounds__(1024) void k_radixsel(RState* st,
    const unsigned long long* __restrict__ cand,
    int* __restrict__ src_all, int* __restrict__ dst_all, float* __restrict__ mask_all)
{
    __shared__ unsigned int lh[256];
    __shared__ unsigned int suf[256];
    __shared__ unsigned int s_tie[8192];
    __shared__ unsigned int s_pref, s_R, s_tiecnt, s_cfth;
    int tid = threadIdx.x;
    int n = (int)st->cand_count;
    int R = st->R;
    if (tid == 0) { s_pref = 0x3F000000u; s_R = (unsigned)R; s_tiecnt = 0; s_cfth = 0; }
    __syncthreads();

    unsigned long long T;
    if (R > 0) {
        for (int p = 0; p < 3; p++) {
            if (tid < 256) lh[tid] = 0;
            __syncthreads();
            unsigned pref = s_pref;
            int sh_d = 16 - 8 * p;
            unsigned pm = 0xFFFFFFFFu << (sh_d + 8);
            for (int i = tid; i < n; i += 1024) {
                unsigned a = (unsigned)(cand[i] >> 32);
                if ((a & pm) == (pref & pm))
                    atomicAdd(&lh[(a >> sh_d) & 255u], 1u);
            }
            __syncthreads();
            if (tid < 256) suf[tid] = lh[tid];
            __syncthreads();
            for (int off = 1; off < 256; off <<= 1) {
                unsigned v = 0;
                if (tid < 256 && tid + off < 256) v = suf[tid + off];
                __syncthreads();
                if (tid < 256) suf[tid] += v;
                __syncthreads();
            }
            if (tid < 256) {
                unsigned Rc = s_R;
                unsigned hi2 = (tid == 255) ? 0u : suf[tid + 1];
                if (suf[tid] >= Rc && hi2 < Rc) {
                    s_pref = pref | ((unsigned)tid << sh_d);
                    s_R = Rc - hi2;
                }
            }
            __syncthreads();
        }
        unsigned Ta = s_pref;
        unsigned Rrem = s_R;
        for (int i = tid; i < n; i += 1024) {
            unsigned long long kv = cand[i];
            if ((unsigned)(kv >> 32) == Ta) {
                unsigned pos = atomicAdd(&s_tiecnt, 1u);
                if (pos < 8192u) s_tie[pos] = (unsigned)(kv & 0xFFFFFFFFull);
            }
        }
        __syncthreads();
        unsigned Cq = s_tiecnt; if (Cq > 8192u) Cq = 8192u;
        if (Rrem >= 1u && Rrem < Cq) {
            for (int i = tid; i < (int)Cq; i += 1024) {
                unsigned me = s_tie[i];
                unsigned r = 0;
                for (int j = 0; j < (int)Cq; j++) r += (s_tie[j] > me) ? 1u : 0u;
                if (r == Rrem - 1u) s_cfth = me;
            }
        }
        __syncthreads();
        T = ((unsigned long long)Ta << 32) | (unsigned long long)s_cfth;
    } else {
        T = ~0ull;
    }

    int lane = tid & 63;
    for (int i0 = 0; i0 < n; i0 += 1024) {
        int i = i0 + tid;
        bool sel = (i < n) && (cand[i] >= T);
        unsigned long long b = __ballot(sel);
        int wc = __popcll(b);
        int basep = 0;
        if (lane == 0 && wc) basep = (int)atomicAdd(&st->sel_count, (unsigned)wc);
        basep = __shfl(basep, 0);
        if (sel) {
            int slot = basep + __popcll(b & ((1ull << lane) - 1ull));
            if (slot < EV_) {
                unsigned flat = 0xFFFFFFFFu - (unsigned)(cand[i] & 0xFFFFFFFFull);
                src_all[E_ + slot] = (int)(flat / (unsigned)K_);
                dst_all[E_ + slot] = (int)(flat % (unsigned)K_);
                mask_all[E_ + slot] = 1.0f;
            }
        }
    }
}

// ---------------- final mixing + pos copy (merged) ----------------
__global__ void k_finalpos(const float* __restrict__ h_local, const int* __restrict__ node2m,
    const float* __restrict__ aggm, const float* __restrict__ degm, const float* __restrict__ h_m,
    const float* __restrict__ m_out, const float* __restrict__ pos,
    float* __restrict__ out_h, float* __restrict__ out_pos)
{
    int idx = blockIdx.x * 256 + threadIdx.x;
    if (idx < N_ * 3) out_pos[idx] = pos[idx];
    if (idx >= N_ * C_) return;
    int i = idx >> 6, c = idx & 63;
    float mval = m_out[i];
    int mi = node2m[i];
    float hh = 0.0f;
    if (mi >= 0) hh = aggm[mi*64 + c] / fmaxf(degm[mi], 1.0f) + h_m[mi*64 + c];
    out_h[idx] = (1.0f - mval) * h_local[idx] + mval * hh;
}

// ---------------- launch ----------------
extern "C" void kernel_launch(void* const* d_in, const int* in_sizes, int n_in,
                              void* d_out, int out_size, void* d_ws, size_t ws_size,
                              hipStream_t stream)
{
    (void)in_sizes; (void)n_in; (void)out_size; (void)ws_size;
    const float* h     = (const float*)d_in[0];
    const float* pos   = (const float*)d_in[1];
    const int*   eidx  = (const int*)d_in[2];
    const float* fc_w1 = (const float*)d_in[3];
    const float* fc_b1 = (const float*)d_in[4];
    const float* fc_w2 = (const float*)d_in[5];
    const float* fc_b2 = (const float*)d_in[6];
    const float* lin_w = (const float*)d_in[7];
    const float* ms_w1 = (const float*)d_in[8];
    const float* ms_b1 = (const float*)d_in[9];
    const float* ms_w2 = (const float*)d_in[10];
    const float* ms_b2 = (const float*)d_in[11];
    const float* vg_wq = (const float*)d_in[12];
    const float* vg_wk = (const float*)d_in[13];

    char* ws = (char*)d_ws;
    float* agg     = (float*)(ws + OFF_AGG);
    float* deg     = (float*)(ws + OFF_DEG);
    float* aggm    = (float*)(ws + OFF_AGGM);
    float* degm    = (float*)(ws + OFF_DEGM);
    int*   rankcnt = (int*)(ws + OFF_RANK);
    float* mask_all = (float*)(ws + OFF_MASKA);
    unsigned char* exist = (unsigned char*)(ws + OFF_EXIST);
    unsigned int* hist = (unsigned int*)(ws + OFF_HIST);
    RState* st     = (RState*)(ws + OFF_STATE);
    unsigned int* cnt0 = (unsigned int*)(ws + OFF_STATE + 64);
    unsigned int* cnt1 = (unsigned int*)(ws + OFF_STATE + 68);
    int*   w0nz    = (int*)(ws + OFF_STATE + 72);
    unsigned int* done_a1 = (unsigned int*)(ws + OFF_STATE + 76);
    float* h_local = (float*)(ws + OFF_HLOCAL);
    unsigned long long* key = (unsigned long long*)(ws + OFF_KEY);
    float* score   = (float*)(ws + OFF_SCORE);
    int*   node2m  = (int*)(ws + OFF_N2M);
    int*   midx    = (int*)(ws + OFF_MIDX);
    float* h_m     = (float*)(ws + OFF_HM);
    float* pos_m   = (float*)(ws + OFF_POSM);
    float* qbuf    = (float*)(ws + OFF_Q);
    float* kbuf    = (float*)(ws + OFF_KBUF);
    int*   src_all = (int*)(ws + OFF_SRCA);
    int*   dst_all = (int*)(ws + OFF_DSTA);
    float* wmax    = (float*)(ws + OFF_WMAX);
    unsigned long long* cand = (unsigned long long*)(ws + OFF_CAND);
    float* edata   = (float*)(ws + OFF_CAND);        // overlays cand (stream-ordered: safe)

    float* out_h   = (float*)d_out;
    float* out_pos = out_h + (size_t)N_ * C_;
    float* out_av  = out_pos + (size_t)N_ * 3;
    float* out_m   = out_av + (size_t)K_ * K_;

    // zero workspace + w0nz
    k_init<<<768, 256, 0, stream>>>(fc_b1, fc_w2, fc_b2, ws);

    // ---- conv 1 on full graph ----
    k_prep<<<E_ / 256, 256, 0, stream>>>(E_, eidx, eidx + E_, nullptr, pos, w0nz, deg, edata, cnt0);
    k_convg<<<768, 256, 0, stream>>>(cnt0, edata, h, fc_w1, fc_b1, fc_w2, fc_b2, lin_w, agg);

    k_hlscore<<<(N_ + 3) / 4, 256, 0, stream>>>(h, agg, deg, ms_w1, ms_b1, ms_w2, ms_b2,
                                                h_local, score, key);

    k_rank<<<dim3((N_ + 255) / 256, 16), 256, 0, stream>>>(key, rankcnt);
    k_scanfin<<<1, 1024, 0, stream>>>(rankcnt, score, node2m, midx, out_m);

    k_mastex<<<500 + E_ / 256, 256, 0, stream>>>(midx, h_local, pos, vg_wq, vg_wk,
        eidx, eidx + E_, node2m, h_m, pos_m, qbuf, kbuf, src_all, dst_all, mask_all, exist);

    // ---- virtual edge selection (flat attention) ----
    k_attn1<<<1024, 256, 0, stream>>>(qbuf, kbuf, exist, out_av, wmax, hist, st, done_a1);
    k_attn2<<<1024, 256, 0, stream>>>(qbuf, kbuf, exist, wmax, st, cand);
    k_radixsel<<<1, 1024, 0, stream>>>(st, cand, src_all, dst_all, mask_all);

    // ---- conv 2 on master graph ----
    k_prep<<<EALL_ / 256, 256, 0, stream>>>(EALL_, src_all, dst_all, mask_all, pos_m, w0nz,
                                            degm, edata, cnt1);
    k_convg<<<768, 256, 0, stream>>>(cnt1, edata, h_m, fc_w1, fc_b1, fc_w2, fc_b2, lin_w, aggm);

    k_finalpos<<<(N_ * C_ + 255) / 256, 256, 0, stream>>>(h_local, node2m, aggm, degm, h_m,
                                                          out_m, pos, out_h, out_pos);
}